// Round 1
// baseline (901.656 us; speedup 1.0000x reference)
//
#include <hip/hip_runtime.h>
#include <stdint.h>

#define NB   64
#define MQ   1024
#define NKV  3072
#define DD   128
#define SKW  2176      // skewed pos row length: 2048 + 128
#define NT2  34        // j-tiles per attention block

typedef float  f32x16 __attribute__((ext_vector_type(16)));
typedef __bf16 bf16x8 __attribute__((ext_vector_type(8)));

static __device__ __forceinline__ unsigned short f2bf(float f) {
    union { float f; unsigned u; } a; a.f = f;
    unsigned u = a.u;
    u += 0x7fffu + ((u >> 16) & 1u);   // RNE
    return (unsigned short)(u >> 16);
}
static __device__ __forceinline__ float bf2f(unsigned short s) {
    union { unsigned u; float f; } a; a.u = ((unsigned)s) << 16; return a.f;
}
static __device__ __forceinline__ unsigned long long pk4(float a, float b, float c, float d) {
    return (unsigned long long)f2bf(a) | ((unsigned long long)f2bf(b) << 16)
         | ((unsigned long long)f2bf(c) << 32) | ((unsigned long long)f2bf(d) << 48);
}

// ---------------------------------------------------------------------------
// prep: Wsum[b,d] = sum_n |value - value_last|  (+ fused key/value passthrough)
// ---------------------------------------------------------------------------
__global__ __launch_bounds__(256) void prep_kernel(
    const float* __restrict__ value, const float* __restrict__ vlast,
    const float* __restrict__ key, float* __restrict__ vout,
    float* __restrict__ kout, float* __restrict__ wsum)
{
    __shared__ float4 red[256];
    int blk = blockIdx.x;            // 256 = 64 b * 4 segments
    int b = blk >> 2, seg = blk & 3;
    int t = threadIdx.x;
    int d4 = t & 31, rg = t >> 5;
    size_t base = (size_t)b * NKV * DD;
    const float4* V  = (const float4*)(value + base);
    const float4* VL = (const float4*)(vlast + base);
    const float4* K  = (const float4*)(key + base);
    float4* VO = (float4*)(vout + base);
    float4* KO = (float4*)(kout + base);
    float ax = 0.f, ay = 0.f, az = 0.f, aw = 0.f;
    int n0 = seg * 768;
    for (int it = 0; it < 96; ++it) {
        int n = n0 + rg + it * 8;
        size_t idx = (size_t)n * 32 + d4;
        float4 v = V[idx], vl = VL[idx], k = K[idx];
        ax += fabsf(v.x - vl.x); ay += fabsf(v.y - vl.y);
        az += fabsf(v.z - vl.z); aw += fabsf(v.w - vl.w);
        VO[idx] = v; KO[idx] = k;
    }
    float4 a4; a4.x = ax; a4.y = ay; a4.z = az; a4.w = aw;
    red[t] = a4;
    __syncthreads();
    if (t < 32) {
        float4 s = red[t];
        #pragma unroll
        for (int g = 1; g < 8; ++g) {
            float4 o = red[t + 32 * g];
            s.x += o.x; s.y += o.y; s.z += o.z; s.w += o.w;
        }
        atomicAdd(&wsum[b * DD + d4 * 4 + 0], s.x);
        atomicAdd(&wsum[b * DD + d4 * 4 + 1], s.y);
        atomicAdd(&wsum[b * DD + d4 * 4 + 2], s.z);
        atomicAdd(&wsum[b * DD + d4 * 4 + 3], s.w);
    }
}

// ---------------------------------------------------------------------------
// pe transpose: peT[k][d] bf16, pre-XOR-swizzled rows ((k&15)<<4 on bytes)
// ---------------------------------------------------------------------------
__global__ __launch_bounds__(256) void pet_kernel(
    const float* __restrict__ pe, unsigned short* __restrict__ peT)
{
    int g = blockIdx.x * 256 + threadIdx.x;   // 32768 threads
    int d = g >> 8;                           // 0..127
    int k0 = (g & 255) * 8;                   // 0..2040
    #pragma unroll
    for (int j = 0; j < 8; ++j) {
        int k = k0 + j;
        float v = pe[(size_t)d * 2048 + k];
        unsigned off = ((unsigned)(2 * d)) ^ ((unsigned)((k & 15) << 4));
        peT[(size_t)k * 128 + (off >> 1)] = f2bf(v);
    }
}

// ---------------------------------------------------------------------------
// shared helpers: W normalization into LDS, Q fragment loader (scaled bf16)
// ---------------------------------------------------------------------------
static __device__ __forceinline__ void load_wn(const float* __restrict__ wsum,
                                               int b, float* Wls, float* mredp)
{
    int t = threadIdx.x;
    if (t < DD) Wls[t] = wsum[b * DD + t];
    __syncthreads();
    if (t < 64) {
        float m = fmaxf(Wls[t], Wls[t + 64]);
        #pragma unroll
        for (int o = 32; o; o >>= 1) m = fmaxf(m, __shfl_xor(m, o));
        if (t == 0) *mredp = m;
    }
    __syncthreads();
    float inv = 0.08838834764831845f / *mredp;   // (1/max) * 1/sqrt(128)
    if (t < DD) Wls[t] *= inv;
    __syncthreads();
}

// qf[ks] element e = qW[i][16*ks + 8*g2 + e]  (k-slot enum sigma = 8*g2+e)
static __device__ __forceinline__ void load_qfrag(
    const float* __restrict__ query, const float* Wls,
    int b, int irow, int g2, bf16x8* qf)
{
    const float* qr = query + ((size_t)b * MQ + irow) * DD;
    #pragma unroll
    for (int ks = 0; ks < 8; ++ks) {
        int d0 = 16 * ks + 8 * g2;
        float4 qa = *(const float4*)(qr + d0);
        float4 qb = *(const float4*)(qr + d0 + 4);
        float4 wa = *(const float4*)(Wls + d0);
        float4 wb = *(const float4*)(Wls + d0 + 4);
        union { unsigned short u[8]; bf16x8 v; } P;
        P.u[0] = f2bf(qa.x * wa.x); P.u[1] = f2bf(qa.y * wa.y);
        P.u[2] = f2bf(qa.z * wa.z); P.u[3] = f2bf(qa.w * wa.w);
        P.u[4] = f2bf(qb.x * wb.x); P.u[5] = f2bf(qb.y * wb.y);
        P.u[6] = f2bf(qb.z * wb.z); P.u[7] = f2bf(qb.w * wb.w);
        qf[ks] = P.v;
    }
}

// ---------------------------------------------------------------------------
// pos producer: posSk[bl][i][(i&127) + k] = (q*W/sqrt(d)) . pe[:,k]   (bf16)
// grid nb*8 blocks (128 q-rows each), 4 waves x 32 rows
// ---------------------------------------------------------------------------
__global__ __launch_bounds__(256, 2) void pos_kernel(
    const float* __restrict__ query, const float* __restrict__ wsum,
    const unsigned short* __restrict__ peT, unsigned short* __restrict__ posSk,
    int b0, int nb)
{
    __shared__ __align__(16) float Wls[DD];
    __shared__ float mred;
    __shared__ __align__(16) unsigned short peL[128 * 128];   // 32 KB

    int nwg = nb * 8;
    int bid = blockIdx.x;
    int sw = (bid & 7) * (nwg >> 3) + (bid >> 3);   // XCD swizzle (nwg % 8 == 0)
    int bl = sw >> 3;
    int b  = b0 + bl;
    int i0 = (sw & 7) * 128;
    int t = threadIdx.x;
    int w = t >> 6, l = t & 63, q = l & 31, g2 = l >> 5;

    load_wn(wsum, b, Wls, &mred);
    bf16x8 qf[8];
    load_qfrag(query, Wls, b, i0 + 32 * w + q, g2, qf);

    unsigned short* psb = posSk + (size_t)bl * MQ * SKW;

    for (int nt = 0; nt < 16; ++nt) {
        __syncthreads();
        {   // stage 128 peT rows (already bf16 + swizzled) -> LDS, linear copy
            const uint4* src = (const uint4*)(peT + (size_t)nt * 16384);
            uint4* dst = (uint4*)peL;
            #pragma unroll
            for (int j = 0; j < 8; ++j) dst[t + 256 * j] = src[t + 256 * j];
        }
        __syncthreads();

        f32x16 acc[4];
        #pragma unroll
        for (int ct = 0; ct < 4; ++ct)
            #pragma unroll
            for (int r = 0; r < 16; ++r) acc[ct][r] = 0.f;

        #pragma unroll
        for (int ks = 0; ks < 8; ++ks) {
            #pragma unroll
            for (int ct = 0; ct < 4; ++ct) {
                int row = 32 * ct + q;
                bf16x8 bfr = *(const bf16x8*)((const char*)peL + row * 256
                        + (((unsigned)(32 * ks + 16 * g2)) ^ ((unsigned)((row & 15) << 4))));
                acc[ct] = __builtin_amdgcn_mfma_f32_32x32x16_bf16(qf[ks], bfr, acc[ct], 0, 0, 0);
            }
        }
        // store skewed: C row = (r&3)+8*(r>>2)+4*g2 (local i), col = l&31 (local k)
        #pragma unroll
        for (int ct = 0; ct < 4; ++ct) {
            #pragma unroll
            for (int r = 0; r < 16; ++r) {
                int il = (r & 3) + 8 * (r >> 2) + 4 * g2;     // 0..31
                int irow = 32 * w + il;                       // i & 127
                int col = irow + nt * 128 + 32 * ct + q;      // (i&127) + k
                psb[(size_t)(i0 + irow) * SKW + col] = f2bf(acc[ct][r]);
            }
        }
    }
}

// ---------------------------------------------------------------------------
// attention: flash over the 2048-band, swapped QK^T (S^T: col=lane&31=q),
// arranged-V LDS for lane-local P->PV, pos read linearly from posSk
// ---------------------------------------------------------------------------
__global__ __launch_bounds__(256, 2) void attn_kernel(
    const float* __restrict__ query, const float* __restrict__ key,
    const float* __restrict__ value, const float* __restrict__ wsum,
    const unsigned short* __restrict__ posSk, float* __restrict__ outp,
    int b0, int nb)
{
    __shared__ __align__(16) float Wls[DD];
    __shared__ float mred;
    __shared__ __align__(16) unsigned short Klds[64 * 128];   // 16 KB, XOR-swizzled rows
    __shared__ __align__(16) unsigned short Varr[64 * 128];   // 16 KB, (ks,g,e)-arranged

    int nwg = nb * 8;
    int bid = blockIdx.x;
    int sw = (bid & 7) * (nwg >> 3) + (bid >> 3);
    int bl = sw >> 3;
    int b  = b0 + bl;
    int i0 = (sw & 7) * 128;
    int t = threadIdx.x;
    int w = t >> 6, l = t & 63, q = l & 31, g2 = l >> 5;

    load_wn(wsum, b, Wls, &mred);
    bf16x8 qf[8];
    load_qfrag(query, Wls, b, i0 + 32 * w + q, g2, qf);

    const float* Kb = key + (size_t)b * NKV * DD;
    const float* Vb = value + (size_t)b * NKV * DD;
    const unsigned short* Prow = posSk + ((size_t)bl * MQ + i0 + 32 * w + q) * SKW;

    float m_run = 0.f, l_run = 0.f;   // m init 0: masked-only tiles give P=0 exactly
    f32x16 oacc[4];
    #pragma unroll
    for (int ct = 0; ct < 4; ++ct)
        #pragma unroll
        for (int r = 0; r < 16; ++r) oacc[ct][r] = 0.f;

    int krow = t >> 2;          // K staging: 0..63
    int kc0 = (t & 3) * 32;
    int vd  = t & 127;          // V staging
    int vq0 = t >> 7;           // 0..1

    for (int t2 = 0; t2 < NT2; ++t2) {
        int j0 = i0 + 64 * t2;
        __syncthreads();
        {   // stage K tile (f32 -> bf16, XOR swizzle (row&15)<<4)
            const float* src = Kb + (size_t)(j0 + krow) * DD + kc0;
            char* drow = (char*)Klds + krow * 256;
            unsigned sw4 = (unsigned)((krow & 15) << 4);
            #pragma unroll
            for (int jj = 0; jj < 8; ++jj) {
                float4 v = *(const float4*)(src + 4 * jj);
                *(unsigned long long*)(drow + (((unsigned)(2 * (kc0 + 4 * jj))) ^ sw4))
                    = pk4(v.x, v.y, v.z, v.w);
            }
        }
        {   // stage V arranged: slot(ks,g,e) holds V[16ks + (e&3)+8*(e>>2)+4g][d]
            #pragma unroll
            for (int p = 0; p < 8; ++p) {
                int rq = vq0 + 2 * p;    // row quad 0..15
                const float* src = Vb + (size_t)(j0 + 4 * rq) * DD + vd;
                float v0 = src[0], v1 = src[DD], v2 = src[2 * DD], v3 = src[3 * DD];
                int ks = rq >> 2, gg = rq & 1, eq = (rq >> 1) & 1;
                *(unsigned long long*)((char*)Varr + (((ks * 2 + gg) * 128 + vd) * 16) + eq * 8)
                    = pk4(v0, v1, v2, v3);
            }
        }
        __syncthreads();

        // pos loads: 8 x 8B per lane, fully consumed cache lines
        uint2 pq[8];
        {
            const unsigned short* pr = Prow + 64 * t2;
            #pragma unroll
            for (int rt = 0; rt < 2; ++rt)
                #pragma unroll
                for (int mq = 0; mq < 4; ++mq)
                    pq[rt * 4 + mq] = *(const uint2*)(pr + (8 * rt + 2 * mq + g2) * 4);
        }

        // S^T = K . Q  (rows kk, cols q)
        f32x16 s[2];
        #pragma unroll
        for (int rt = 0; rt < 2; ++rt)
            #pragma unroll
            for (int r = 0; r < 16; ++r) s[rt][r] = 0.f;
        #pragma unroll
        for (int rt = 0; rt < 2; ++rt) {
            const char* kp = (const char*)Klds + (32 * rt + q) * 256;
            unsigned sw4 = (unsigned)((q & 15) << 4);   // (32rt+q)&15 == q&15
            #pragma unroll
            for (int ks = 0; ks < 8; ++ks) {
                bf16x8 a = *(const bf16x8*)(kp + (((unsigned)(32 * ks + 16 * g2)) ^ sw4));
                s[rt] = __builtin_amdgcn_mfma_f32_32x32x16_bf16(a, qf[ks], s[rt], 0, 0, 0);
            }
        }

        // add pos, mask window, row max
        float mt = -1e30f;
        #pragma unroll
        for (int rt = 0; rt < 2; ++rt) {
            int kb = 64 * t2 + 32 * rt - 32 * w;
            bool fv = (kb >= 31) && (kb + 31 < 2048);
            #pragma unroll
            for (int r = 0; r < 16; ++r) {
                int kk_in = (r & 3) + 8 * (r >> 2) + 4 * g2;
                uint2 u2 = pq[rt * 4 + (r >> 2)];
                unsigned uu = (r & 2) ? u2.y : u2.x;
                float posv = bf2f((unsigned short)((r & 1) ? (uu >> 16) : (uu & 0xffffu)));
                float v = s[rt][r] + posv;
                if (!fv) {
                    int k = kb + kk_in - q;
                    v = ((unsigned)k < 2048u) ? v : -1e30f;
                }
                s[rt][r] = v;
                mt = fmaxf(mt, v);
            }
        }
        mt = fmaxf(mt, __shfl_xor(mt, 32));
        float mnew = fmaxf(m_run, mt);
        float scl = __expf(m_run - mnew);
        float rsum = 0.f;
        #pragma unroll
        for (int rt = 0; rt < 2; ++rt)
            #pragma unroll
            for (int r = 0; r < 16; ++r) {
                float p = __expf(s[rt][r] - mnew);
                s[rt][r] = p;
                rsum += p;
            }
        rsum += __shfl_xor(rsum, 32);
        l_run = l_run * scl + rsum;
        m_run = mnew;

        // rescale O accumulator (factor indexed by out-row, fetched via shfl)
        #pragma unroll
        for (int r = 0; r < 16; ++r) {
            int il = (r & 3) + 8 * (r >> 2) + 4 * g2;
            float f = __shfl(scl, (l & 32) | il);
            #pragma unroll
            for (int ct = 0; ct < 4; ++ct) oacc[ct][r] *= f;
        }

        // PV: A = P (lane-local from S^T acc), B = Varr (single b128 per frag)
        #pragma unroll
        for (int ks = 0; ks < 4; ++ks) {
            int rt = ks >> 1, hf = ks & 1;
            union { unsigned short u[8]; bf16x8 v; } pf;
            #pragma unroll
            for (int e = 0; e < 8; ++e) pf.u[e] = f2bf(s[rt][8 * hf + e]);
            #pragma unroll
            for (int ct = 0; ct < 4; ++ct) {
                bf16x8 vb = *(const bf16x8*)((const char*)Varr
                        + (((ks * 2 + g2) * 128 + 32 * ct + q) * 16));
                oacc[ct] = __builtin_amdgcn_mfma_f32_32x32x16_bf16(pf.v, vb, oacc[ct], 0, 0, 0);
            }
        }
    }

    // epilogue: divide by l and store f32
    float inv = 1.0f / l_run;
    float* orow = outp + ((size_t)b * MQ + i0 + 32 * w) * DD;
    #pragma unroll
    for (int r = 0; r < 16; ++r) {
        int il = (r & 3) + 8 * (r >> 2) + 4 * g2;
        float f = __shfl(inv, (l & 32) | il);
        #pragma unroll
        for (int ct = 0; ct < 4; ++ct)
            orow[(size_t)il * DD + 32 * ct + q] = oacc[ct][r] * f;
    }
}

// ---------------------------------------------------------------------------
extern "C" void kernel_launch(void* const* d_in, const int* in_sizes, int n_in,
                              void* d_out, int out_size, void* d_ws, size_t ws_size,
                              hipStream_t stream)
{
    const float* query = (const float*)d_in[0];
    const float* key   = (const float*)d_in[1];
    const float* value = (const float*)d_in[2];
    const float* keype = (const float*)d_in[3];
    const float* vlast = (const float*)d_in[4];
    float* out  = (float*)d_out;
    float* kout = out + (size_t)NB * MQ * DD;
    float* vout = kout + (size_t)NB * NKV * DD;

    char* ws = (char*)d_ws;
    float* wsum = (float*)ws;                                  // 32 KB @0
    unsigned short* peT = (unsigned short*)(ws + 65536);       // 512 KB @64 KB
    unsigned short* posSk = (unsigned short*)(ws + (1 << 20)); // chunked region @1 MB
    size_t perB = (size_t)MQ * SKW * sizeof(unsigned short);   // 4,456,448 B per b
    size_t avail = (ws_size > (size_t)(1 << 20)) ? ws_size - (1 << 20) : 0;
    int chunk = (int)(avail / perB);
    if (chunk < 1) chunk = 1;
    if (chunk > NB) chunk = NB;

    hipMemsetAsync(wsum, 0, NB * DD * sizeof(float), stream);
    prep_kernel<<<256, 256, 0, stream>>>(value, vlast, key, vout, kout, wsum);
    pet_kernel<<<128, 256, 0, stream>>>(keype, peT);
    for (int b0 = 0; b0 < NB; b0 += chunk) {
        int nb = (NB - b0 < chunk) ? (NB - b0) : chunk;
        pos_kernel<<<nb * 8, 256, 0, stream>>>(query, wsum, peT, posSk, b0, nb);
        attn_kernel<<<nb * 8, 256, 0, stream>>>(query, key, value, wsum, posSk, out, b0, nb);
    }
}